// Round 2
// baseline (1027.195 us; speedup 1.0000x reference)
//
#include <hip/hip_runtime.h>
#include <math.h>

#define GRIDN    128
#define NRAYS    16384
#define STEPSZ   0.5f
#define MAXSTEPS 320
#define SEGS     32
#define SPS      (MAXSTEPS / SEGS)   // 10 steps per segment
#define RPB      8                   // rays per block
#define TPB      (RPB * SEGS)        // 256 threads
#define NVOX     (GRIDN * GRIDN * GRIDN)
#define PACK_BYTES ((size_t)NVOX * 128)   // 32 floats (128 B) per voxel, 7 used float4s

// ---------------------------------------------------------------------------
// Prologue: repack density+SH into one 128B-aligned record per GRID VOXEL,
// indexed directly by cell id (kills the links indirection + misaligned rows).
// Record: f[0]=density, f[1..27]=sh, f[28..31]=pad (never read/written).
// ---------------------------------------------------------------------------
__global__ __launch_bounds__(256, 8)
void repack_kernel(const int*   __restrict__ links,
                   const float* __restrict__ density,
                   const float* __restrict__ sh,
                   float4*      __restrict__ pack)
{
    const int idx = blockIdx.x * 256 + threadIdx.x;
    if (idx >= NVOX) return;
    const int lnk = links[idx];
    float s[28];
    if (lnk >= 0) {
        s[0] = density[lnk];
        const float* row = sh + (size_t)lnk * 27;
        #pragma unroll
        for (int k = 0; k < 27; k++) s[1 + k] = row[k];
    } else {
        #pragma unroll
        for (int k = 0; k < 28; k++) s[k] = 0.0f;
    }
    float4* pw = pack + (size_t)idx * 8;
    #pragma unroll
    for (int j = 0; j < 7; j++)
        pw[j] = make_float4(s[4 * j], s[4 * j + 1], s[4 * j + 2], s[4 * j + 3]);
}

// ---------------------------------------------------------------------------
// March: one thread = one (ray, segment); segments stitched via transmittance
// decomposition. Depth-variance pass fused via o_v = D2 - 2*E*D1 + E^2*A.
// ---------------------------------------------------------------------------
template <bool PACKED>
__global__ __launch_bounds__(TPB, 6)
void march_kernel(const float* __restrict__ origins,
                  const float* __restrict__ dirs,
                  const int*   __restrict__ links,
                  const float* __restrict__ density,
                  const float* __restrict__ sh,
                  const float4* __restrict__ pack,
                  float* __restrict__ out)
{
    __shared__ float part[SEGS][RPB][8];

    const int tid = threadIdx.x;
    const int r   = tid & (RPB - 1);
    const int seg = tid / RPB;
    const int ray = blockIdx.x * RPB + r;

    // ---- ray setup ----
    const float owx = origins[ray * 3 + 0];
    const float owy = origins[ray * 3 + 1];
    const float owz = origins[ray * 3 + 2];
    const float dwx = dirs[ray * 3 + 0];
    const float dwy = dirs[ray * 3 + 1];
    const float dwz = dirs[ray * 3 + 2];

    const float invn = 1.0f / sqrtf(dwx * dwx + dwy * dwy + dwz * dwz);
    const float vx = dwx * invn, vy = dwy * invn, vz = dwz * invn;

    const float ox = 63.5f + owx * 64.0f;
    const float oy = 63.5f + owy * 64.0f;
    const float oz = 63.5f + owz * 64.0f;

    const float sxx = vx * 64.0f, syy = vy * 64.0f, szz = vz * 64.0f;
    const float ds  = 1.0f / sqrtf(sxx * sxx + syy * syy + szz * szz);
    const float dx = sxx * ds, dy = syy * ds, dz = szz * ds;

    float shm[9];
    shm[0] = 0.28209479177387814f;
    shm[1] = -0.4886025119029199f * vy;
    shm[2] =  0.4886025119029199f * vz;
    shm[3] = -0.4886025119029199f * vx;
    shm[4] =  1.0925484305920792f * vx * vy;
    shm[5] = -1.0925484305920792f * vy * vz;
    shm[6] =  0.31539156525252005f * (2.0f * vz * vz - vx * vx - vy * vy);
    shm[7] = -1.0925484305920792f * vx * vz;
    shm[8] =  0.5462742152960396f * (vx * vx - vy * vy);

    float t0 = 0.0f, tmax = 1e9f;
    {
        const float o3[3] = { ox, oy, oz };
        const float d3[3] = { dx, dy, dz };
        #pragma unroll
        for (int a = 0; a < 3; a++) {
            if (d3[a] != 0.0f) {
                float inv = 1.0f / d3[a];
                float ta = (-0.5f  - o3[a]) * inv;
                float tb = (127.5f - o3[a]) * inv;
                t0   = fmaxf(t0,   fminf(ta, tb));
                tmax = fminf(tmax, fmaxf(ta, tb));
            }
        }
    }

    float ll = 0.0f;           // local log-light
    float light = 1.0f;        // exp(ll), maintained multiplicatively
    float aR = 0, aG = 0, aB = 0, aA = 0, aD1 = 0, aD2 = 0;

    int cached_cell = -1;
    float csig[8], cr0[8], cr1[8], cr2[8];

    const int k0 = seg * SPS;
    for (int i = 0; i < SPS; i++) {
        const float t = t0 + (float)(k0 + i) * STEPSZ;
        if (t > tmax) break;

        float px = fminf(fmaxf(ox + t * dx, 0.0f), 127.0f);
        float py = fminf(fmaxf(oy + t * dy, 0.0f), 127.0f);
        float pz = fminf(fmaxf(oz + t * dz, 0.0f), 127.0f);
        const int lx = min(max((int)px, 0), 126);
        const int ly = min(max((int)py, 0), 126);
        const int lz = min(max((int)pz, 0), 126);
        const float fx = px - (float)lx;
        const float fy = py - (float)ly;
        const float fz = pz - (float)lz;

        const int cell = (lx << 14) | (ly << 7) | lz;
        if (cell != cached_cell) {
            cached_cell = cell;
            #pragma unroll
            for (int c = 0; c < 8; c++) {
                const int cdx = (c >> 2) & 1, cdy = (c >> 1) & 1, cdz = c & 1;
                const int idx = cell + (cdx << 14) + (cdy << 7) + cdz;
                float sg, q0, q1, q2;
                if (PACKED) {
                    const float4* pr = pack + (size_t)idx * 8;
                    const float4 v0 = pr[0], v1 = pr[1], v2 = pr[2], v3 = pr[3];
                    const float4 v4 = pr[4], v5 = pr[5], v6 = pr[6];
                    sg = v0.x;
                    q0 = v0.y*shm[0] + v0.z*shm[1] + v0.w*shm[2] + v1.x*shm[3]
                       + v1.y*shm[4] + v1.z*shm[5] + v1.w*shm[6] + v2.x*shm[7]
                       + v2.y*shm[8];
                    q1 = v2.z*shm[0] + v2.w*shm[1] + v3.x*shm[2] + v3.y*shm[3]
                       + v3.z*shm[4] + v3.w*shm[5] + v4.x*shm[6] + v4.y*shm[7]
                       + v4.z*shm[8];
                    q2 = v4.w*shm[0] + v5.x*shm[1] + v5.y*shm[2] + v5.z*shm[3]
                       + v5.w*shm[4] + v6.x*shm[5] + v6.y*shm[6] + v6.z*shm[7]
                       + v6.w*shm[8];
                } else {
                    const int lnk = links[idx];
                    sg = 0.0f; q0 = 0.0f; q1 = 0.0f; q2 = 0.0f;
                    if (lnk >= 0) {
                        sg = density[lnk];
                        const float* row = sh + (size_t)lnk * 27;
                        #pragma unroll
                        for (int k = 0; k < 9; k++) {
                            const float m = shm[k];
                            q0 += m * row[k];
                            q1 += m * row[9 + k];
                            q2 += m * row[18 + k];
                        }
                    }
                }
                csig[c] = sg; cr0[c] = q0; cr1[c] = q1; cr2[c] = q2;
            }
        }

        const float gx1 = fx, gx0 = 1.0f - fx;
        const float gy1 = fy, gy0 = 1.0f - fy;
        const float gz1 = fz, gz0 = 1.0f - fz;
        float w[8];
        w[0] = gx0*gy0*gz0; w[1] = gx0*gy0*gz1; w[2] = gx0*gy1*gz0; w[3] = gx0*gy1*gz1;
        w[4] = gx1*gy0*gz0; w[5] = gx1*gy0*gz1; w[6] = gx1*gy1*gz0; w[7] = gx1*gy1*gz1;

        float sigma = 0, c0 = 0, c1 = 0, c2 = 0;
        #pragma unroll
        for (int c = 0; c < 8; c++) {
            sigma += w[c] * csig[c];
            c0    += w[c] * cr0[c];
            c1    += w[c] * cr1[c];
            c2    += w[c] * cr2[c];
        }

        const float la = -STEPSZ * fmaxf(sigma, 0.0f) * ds;
        const float e  = __expf(la);
        const float ws = light * (1.0f - e);
        c0 = fmaxf(c0 + 0.5f, 0.0f);
        c1 = fmaxf(c1 + 0.5f, 0.0f);
        c2 = fmaxf(c2 + 0.5f, 0.0f);

        aR += ws * c0; aG += ws * c1; aB += ws * c2;
        aA += ws;
        const float dd = t * ds;
        aD1 += ws * dd;
        aD2 += ws * dd * dd;
        light *= e;
        ll    += la;
    }

    part[seg][r][0] = aR;  part[seg][r][1] = aG;  part[seg][r][2] = aB;
    part[seg][r][3] = aA;  part[seg][r][4] = aD1; part[seg][r][5] = aD2;
    part[seg][r][6] = ll;
    __syncthreads();

    if (tid < RPB) {
        float pre = 0.0f;
        float R = 0, G = 0, Bc = 0, A = 0, D1 = 0, D2 = 0;
        for (int s = 0; s < SEGS; s++) {
            const float T = __expf(pre);
            R  += T * part[s][tid][0];
            G  += T * part[s][tid][1];
            Bc += T * part[s][tid][2];
            A  += T * part[s][tid][3];
            D1 += T * part[s][tid][4];
            D2 += T * part[s][tid][5];
            pre += part[s][tid][6];
        }
        const float bg    = __expf(pre);
        const float denom = fmaxf(A, 1e-10f);
        const float E     = D1 / denom;
        const float ov    = D2 - 2.0f * E * D1 + E * E * A;

        const int o = (blockIdx.x * RPB + tid) * 6;
        out[o + 0] = R  + bg;
        out[o + 1] = G  + bg;
        out[o + 2] = Bc + bg;
        out[o + 3] = A;
        out[o + 4] = E;
        out[o + 5] = ov / denom;
    }
}

extern "C" void kernel_launch(void* const* d_in, const int* in_sizes, int n_in,
                              void* d_out, int out_size, void* d_ws, size_t ws_size,
                              hipStream_t stream) {
    const float* origins = (const float*)d_in[0];
    const float* dirs    = (const float*)d_in[1];
    const int*   links   = (const int*)d_in[2];
    const float* density = (const float*)d_in[3];
    const float* sh      = (const float*)d_in[4];
    float* out = (float*)d_out;

    dim3 mgrid(NRAYS / RPB);   // 2048 blocks
    dim3 mblock(TPB);          // 256 threads = 8 rays x 32 segments

    if (ws_size >= PACK_BYTES) {
        float4* pack = (float4*)d_ws;
        repack_kernel<<<dim3((NVOX + 255) / 256), dim3(256), 0, stream>>>(
            links, density, sh, pack);
        march_kernel<true><<<mgrid, mblock, 0, stream>>>(
            origins, dirs, links, density, sh, pack, out);
    } else {
        march_kernel<false><<<mgrid, mblock, 0, stream>>>(
            origins, dirs, links, density, sh, (const float4*)nullptr, out);
    }
}

// Round 3
// 616.224 us; speedup vs baseline: 1.6669x; 1.6669x over previous
//
#include <hip/hip_runtime.h>
#include <math.h>

#define GRIDN    128
#define NRAYS    16384
#define STEPSZ   0.5f
#define MAXSTEPS 320
#define SEGS     32
#define SPS      (MAXSTEPS / SEGS)   // 10 steps per segment
#define RPB      8                   // rays per block
#define TPB      (RPB * SEGS)        // 256 threads
#define NVOX     (GRIDN * GRIDN * GRIDN)
// fp16 record: 32 halves (64 B) per data ROW: [0]=density, [1..27]=sh, pad.
// +1 sentinel zero record at row NVOX for links<0.
#define PACK_BYTES ((size_t)(NVOX + 1) * 64)

typedef _Float16 half8 __attribute__((ext_vector_type(8)));

// ---------------------------------------------------------------------------
// Prologue: row-space repack, fully coalesced via LDS transpose.
// Each wave handles 64 rows: reads 64*27 contiguous floats coalesced into LDS,
// then each lane converts its row to fp16 and writes a 64-B record.
// ---------------------------------------------------------------------------
__global__ __launch_bounds__(256, 5)
void repack_kernel(const float* __restrict__ density,
                   const float* __restrict__ sh,
                   _Float16*    __restrict__ pack)
{
    __shared__ float buf[4][64 * 27];   // 27648 B/block
    const int lane = threadIdx.x & 63;
    const int wv   = threadIdx.x >> 6;
    const size_t rowbase = ((size_t)blockIdx.x * 4 + wv) * 64;

    const float* src = sh + rowbase * 27;
    float* b = buf[wv];
    #pragma unroll
    for (int j = 0; j < 27; j++)
        b[j * 64 + lane] = src[j * 64 + lane];   // coalesced, covers 64 rows

    const size_t row = rowbase + lane;
    const float dens = density[row];             // coalesced
    __syncthreads();

    const float* myrow = b + lane * 27;          // stride 27: conflict-free
    __align__(16) _Float16 rec[32];
    rec[0] = (_Float16)dens;
    #pragma unroll
    for (int k = 0; k < 27; k++) rec[1 + k] = (_Float16)myrow[k];
    #pragma unroll
    for (int k = 28; k < 32; k++) rec[k] = (_Float16)0.0f;

    uint4* dst = (uint4*)(pack + row * 32);
    const uint4* rp = (const uint4*)rec;
    dst[0] = rp[0]; dst[1] = rp[1]; dst[2] = rp[2]; dst[3] = rp[3];

    if (blockIdx.x == 0 && threadIdx.x == 0) {   // zero sentinel row
        uint4 z = make_uint4(0u, 0u, 0u, 0u);
        uint4* s = (uint4*)(pack + (size_t)NVOX * 32);
        s[0] = z; s[1] = z; s[2] = z; s[3] = z;
    }
}

// ---------------------------------------------------------------------------
// March: one thread = one (ray, segment); segments stitched via transmittance
// decomposition. Depth-variance pass fused via o_v = D2 - 2*E*D1 + E^2*A.
// ---------------------------------------------------------------------------
template <bool PACKED>
__global__ __launch_bounds__(TPB, 6)
void march_kernel(const float* __restrict__ origins,
                  const float* __restrict__ dirs,
                  const int*   __restrict__ links,
                  const float* __restrict__ density,
                  const float* __restrict__ sh,
                  const _Float16* __restrict__ pack,
                  float* __restrict__ out)
{
    __shared__ float part[SEGS][RPB][8];

    const int tid = threadIdx.x;
    const int r   = tid & (RPB - 1);
    const int seg = tid / RPB;
    const int ray = blockIdx.x * RPB + r;

    // ---- ray setup ----
    const float owx = origins[ray * 3 + 0];
    const float owy = origins[ray * 3 + 1];
    const float owz = origins[ray * 3 + 2];
    const float dwx = dirs[ray * 3 + 0];
    const float dwy = dirs[ray * 3 + 1];
    const float dwz = dirs[ray * 3 + 2];

    const float invn = 1.0f / sqrtf(dwx * dwx + dwy * dwy + dwz * dwz);
    const float vx = dwx * invn, vy = dwy * invn, vz = dwz * invn;

    const float ox = 63.5f + owx * 64.0f;
    const float oy = 63.5f + owy * 64.0f;
    const float oz = 63.5f + owz * 64.0f;

    const float sxx = vx * 64.0f, syy = vy * 64.0f, szz = vz * 64.0f;
    const float ds  = 1.0f / sqrtf(sxx * sxx + syy * syy + szz * szz);
    const float dx = sxx * ds, dy = syy * ds, dz = szz * ds;

    float shm[9];
    shm[0] = 0.28209479177387814f;
    shm[1] = -0.4886025119029199f * vy;
    shm[2] =  0.4886025119029199f * vz;
    shm[3] = -0.4886025119029199f * vx;
    shm[4] =  1.0925484305920792f * vx * vy;
    shm[5] = -1.0925484305920792f * vy * vz;
    shm[6] =  0.31539156525252005f * (2.0f * vz * vz - vx * vx - vy * vy);
    shm[7] = -1.0925484305920792f * vx * vz;
    shm[8] =  0.5462742152960396f * (vx * vx - vy * vy);

    float t0 = 0.0f, tmax = 1e9f;
    {
        const float o3[3] = { ox, oy, oz };
        const float d3[3] = { dx, dy, dz };
        #pragma unroll
        for (int a = 0; a < 3; a++) {
            if (d3[a] != 0.0f) {
                float inv = 1.0f / d3[a];
                float ta = (-0.5f  - o3[a]) * inv;
                float tb = (127.5f - o3[a]) * inv;
                t0   = fmaxf(t0,   fminf(ta, tb));
                tmax = fminf(tmax, fmaxf(ta, tb));
            }
        }
    }

    float ll = 0.0f;
    float light = 1.0f;
    float aR = 0, aG = 0, aB = 0, aA = 0, aD1 = 0, aD2 = 0;

    int cached_cell = -1;
    float csig[8], cr0[8], cr1[8], cr2[8];

    const int k0 = seg * SPS;
    for (int i = 0; i < SPS; i++) {
        const float t = t0 + (float)(k0 + i) * STEPSZ;
        if (t > tmax) break;

        float px = fminf(fmaxf(ox + t * dx, 0.0f), 127.0f);
        float py = fminf(fmaxf(oy + t * dy, 0.0f), 127.0f);
        float pz = fminf(fmaxf(oz + t * dz, 0.0f), 127.0f);
        const int lx = min(max((int)px, 0), 126);
        const int ly = min(max((int)py, 0), 126);
        const int lz = min(max((int)pz, 0), 126);
        const float fx = px - (float)lx;
        const float fy = py - (float)ly;
        const float fz = pz - (float)lz;

        const int cell = (lx << 14) | (ly << 7) | lz;
        if (cell != cached_cell) {
            cached_cell = cell;
            if (PACKED) {
                int rows[8];
                #pragma unroll
                for (int c = 0; c < 8; c++) {
                    const int cdx = (c >> 2) & 1, cdy = (c >> 1) & 1, cdz = c & 1;
                    const int lnk = links[cell + (cdx << 14) + (cdy << 7) + cdz];
                    rows[c] = (lnk >= 0) ? lnk : NVOX;   // sentinel zero record
                }
                #pragma unroll
                for (int c = 0; c < 8; c++) {
                    const half8* pr = (const half8*)(pack + (size_t)rows[c] * 32);
                    const half8 h0 = pr[0], h1 = pr[1], h2 = pr[2], h3 = pr[3];
                    csig[c] = (float)h0[0];
                    cr0[c] = shm[0]*(float)h0[1] + shm[1]*(float)h0[2] + shm[2]*(float)h0[3]
                           + shm[3]*(float)h0[4] + shm[4]*(float)h0[5] + shm[5]*(float)h0[6]
                           + shm[6]*(float)h0[7] + shm[7]*(float)h1[0] + shm[8]*(float)h1[1];
                    cr1[c] = shm[0]*(float)h1[2] + shm[1]*(float)h1[3] + shm[2]*(float)h1[4]
                           + shm[3]*(float)h1[5] + shm[4]*(float)h1[6] + shm[5]*(float)h1[7]
                           + shm[6]*(float)h2[0] + shm[7]*(float)h2[1] + shm[8]*(float)h2[2];
                    cr2[c] = shm[0]*(float)h2[3] + shm[1]*(float)h2[4] + shm[2]*(float)h2[5]
                           + shm[3]*(float)h2[6] + shm[4]*(float)h2[7] + shm[5]*(float)h3[0]
                           + shm[6]*(float)h3[1] + shm[7]*(float)h3[2] + shm[8]*(float)h3[3];
                }
            } else {
                #pragma unroll
                for (int c = 0; c < 8; c++) {
                    const int cdx = (c >> 2) & 1, cdy = (c >> 1) & 1, cdz = c & 1;
                    const int idx = cell + (cdx << 14) + (cdy << 7) + cdz;
                    const int lnk = links[idx];
                    float sg = 0, q0 = 0, q1 = 0, q2 = 0;
                    if (lnk >= 0) {
                        sg = density[lnk];
                        const float* row = sh + (size_t)lnk * 27;
                        #pragma unroll
                        for (int k = 0; k < 9; k++) {
                            const float m = shm[k];
                            q0 += m * row[k];
                            q1 += m * row[9 + k];
                            q2 += m * row[18 + k];
                        }
                    }
                    csig[c] = sg; cr0[c] = q0; cr1[c] = q1; cr2[c] = q2;
                }
            }
        }

        const float gx1 = fx, gx0 = 1.0f - fx;
        const float gy1 = fy, gy0 = 1.0f - fy;
        const float gz1 = fz, gz0 = 1.0f - fz;
        float w[8];
        w[0] = gx0*gy0*gz0; w[1] = gx0*gy0*gz1; w[2] = gx0*gy1*gz0; w[3] = gx0*gy1*gz1;
        w[4] = gx1*gy0*gz0; w[5] = gx1*gy0*gz1; w[6] = gx1*gy1*gz0; w[7] = gx1*gy1*gz1;

        float sigma = 0, c0 = 0, c1 = 0, c2 = 0;
        #pragma unroll
        for (int c = 0; c < 8; c++) {
            sigma += w[c] * csig[c];
            c0    += w[c] * cr0[c];
            c1    += w[c] * cr1[c];
            c2    += w[c] * cr2[c];
        }

        const float la = -STEPSZ * fmaxf(sigma, 0.0f) * ds;
        const float e  = __expf(la);
        const float ws = light * (1.0f - e);
        c0 = fmaxf(c0 + 0.5f, 0.0f);
        c1 = fmaxf(c1 + 0.5f, 0.0f);
        c2 = fmaxf(c2 + 0.5f, 0.0f);

        aR += ws * c0; aG += ws * c1; aB += ws * c2;
        aA += ws;
        const float dd = t * ds;
        aD1 += ws * dd;
        aD2 += ws * dd * dd;
        light *= e;
        ll    += la;
    }

    part[seg][r][0] = aR;  part[seg][r][1] = aG;  part[seg][r][2] = aB;
    part[seg][r][3] = aA;  part[seg][r][4] = aD1; part[seg][r][5] = aD2;
    part[seg][r][6] = ll;
    __syncthreads();

    if (tid < RPB) {
        float pre = 0.0f;
        float R = 0, G = 0, Bc = 0, A = 0, D1 = 0, D2 = 0;
        for (int s = 0; s < SEGS; s++) {
            const float T = __expf(pre);
            R  += T * part[s][tid][0];
            G  += T * part[s][tid][1];
            Bc += T * part[s][tid][2];
            A  += T * part[s][tid][3];
            D1 += T * part[s][tid][4];
            D2 += T * part[s][tid][5];
            pre += part[s][tid][6];
        }
        const float bg    = __expf(pre);
        const float denom = fmaxf(A, 1e-10f);
        const float E     = D1 / denom;
        const float ov    = D2 - 2.0f * E * D1 + E * E * A;

        const int o = (blockIdx.x * RPB + tid) * 6;
        out[o + 0] = R  + bg;
        out[o + 1] = G  + bg;
        out[o + 2] = Bc + bg;
        out[o + 3] = A;
        out[o + 4] = E;
        out[o + 5] = ov / denom;
    }
}

extern "C" void kernel_launch(void* const* d_in, const int* in_sizes, int n_in,
                              void* d_out, int out_size, void* d_ws, size_t ws_size,
                              hipStream_t stream) {
    const float* origins = (const float*)d_in[0];
    const float* dirs    = (const float*)d_in[1];
    const int*   links   = (const int*)d_in[2];
    const float* density = (const float*)d_in[3];
    const float* sh      = (const float*)d_in[4];
    float* out = (float*)d_out;

    dim3 mgrid(NRAYS / RPB);   // 2048 blocks
    dim3 mblock(TPB);          // 256 threads = 8 rays x 32 segments

    if (ws_size >= PACK_BYTES) {
        _Float16* pack = (_Float16*)d_ws;
        repack_kernel<<<dim3(NVOX / 256), dim3(256), 0, stream>>>(density, sh, pack);
        march_kernel<true><<<mgrid, mblock, 0, stream>>>(
            origins, dirs, links, density, sh, pack, out);
    } else {
        march_kernel<false><<<mgrid, mblock, 0, stream>>>(
            origins, dirs, links, density, sh, (const _Float16*)nullptr, out);
    }
}